// Round 15
// baseline (2454.545 us; speedup 1.0000x reference)
//
#include <hip/hip_runtime.h>
#include <math.h>

// Problem: inputs (32,64,64,64) BCHW fp32, codebook (1024,64) fp32
// out: [loss][q_st 8388608][perp][one-hot 134217728] fp32
typedef _Float16 half8 __attribute__((ext_vector_type(8)));
typedef float f32x4 __attribute__((ext_vector_type(4)));

#define Q_OFF    1
#define PERP_OFF 8388609
#define OH_OFF   8388610
#define LOSS_N   8388608.0f
// one-hot floats [8388610, 142606338); 16B-aligned float4 span from float
// 8388612: 33554431 float4s; strays 8388610,8388611 / 142606336,142606337
#define OH_F4_BASE 8388612
#define OH_NF4     33554431
#define N_FILL_BLK 131072      // ceil(OH_NF4/256); one float4 per thread
#define GRID_TOT   132096      // + 1024 compute blocks

// ws byte layout:
// [0,4096)         cnorm (1024 f32)
// [4096,8192)      hist  (1024 int)
// [8192,12288)     partial (1024 f32)
// [16384,278528)   cb2: 64 tiles x 4KB; tile = 16 codes:
//                  [hi ks0 1KB | hi ks1 1KB | lo ks0 1KB | lo ks1 1KB],
//                  within each 1KB: code c (0..15) x 64B (dims g*8+i, g=0..3)
// [278528,802816)  idx (131072 int)
#define CB2_OFF_B 16384
#define IDX_OFF_W 69632   // 278528/4

__global__ __launch_bounds__(256) void k0_prep(const float* __restrict__ cb,
                                               float* __restrict__ cnorm,
                                               int* __restrict__ hist,
                                               char* __restrict__ cb2) {
  int k = blockIdx.x * 256 + threadIdx.x;   // grid=4 -> k in [0,1024)
  hist[k] = 0;
  const float* row = cb + (size_t)k * 64;
  const float4* r4 = (const float4*)row;
  float s = 0.f;
#pragma unroll
  for (int i = 0; i < 16; ++i) {
    float4 v = r4[i];
    s += v.x * v.x + v.y * v.y + v.z * v.z + v.w * v.w;
  }
  cnorm[k] = s;

  // fp16 hi/lo split, tile-contiguous layout for dense per-wave loads.
  int tile = k >> 4, c = k & 15;
  char* base = cb2 + tile * 4096;
#pragma unroll
  for (int d16 = 0; d16 < 8; ++d16) {
    half8 hh, ll;
#pragma unroll
    for (int i = 0; i < 8; ++i) {
      float v = row[d16 * 8 + i];
      _Float16 h = (_Float16)v;
      hh[i] = h;
      ll[i] = (_Float16)(v - (float)h);
    }
    int off = (d16 >> 2) * 1024 + c * 64 + (d16 & 3) * 16;  // ks | code | g
    *(half8*)(base + off) = hh;          // hi
    *(half8*)(base + 2048 + off) = ll;   // lo
  }
}

// MEGA-GRID fused fill+compute (132096 blocks x 256 thr):
//   FILL blocks (131072): ONE float4 store per thread (4KB/block) — the
//     driver-fill config. Theory (R14): looped-store kernels cap at ~2.8TB/s
//     (store-queue serialization); one-shot mega-grids run at the CP dispatch
//     rate ~1640 wg/us = 6.7 TB/s (the harness's own 2.28GB fill: 557K wg in
//     340us). Wave issues 1 store, retires; no queue buildup.
//   COMPUTE blocks (1024) at (bid&63)==32, bid>>6 < 1024 — spread across the
//     FIRST HALF of the dispatch stream so they co-run with the fill instead
//     of serializing (computes occupy <=2 of 4 CU slots on average early).
//     Verbatim R9 MFMA structure (44 VGPR): 128 points, all 1024 codes,
//     B-frags from L2, 3-term fp16-split distances (exact argmin vs fp32,
//     verified R4-R14). Writes idx/hist/q_st/partial; ones deferred to
//     k_final (fill/ones race otherwise).
__global__ __launch_bounds__(256, 4) void k1_mega(
    const float* __restrict__ in, const float* __restrict__ cb,
    const char* __restrict__ cb2, const float* __restrict__ cnorm,
    int* __restrict__ hist, float* __restrict__ partial,
    int* __restrict__ idx, float* __restrict__ out) {
  __shared__ int bestk_s[128];
  __shared__ float red[256];

  const int tid = threadIdx.x;
  const int bid = blockIdx.x;
  const int q6 = bid >> 6, r6 = bid & 63;
  const bool is_compute = (r6 == 32) && (q6 < 1024);

  if (!is_compute) {
    // ---- FILL: one float4 per thread ----
    const int nc = (q6 < 1024) ? (q6 + (r6 > 32 ? 1 : 0)) : 1024;
    const int fi = bid - nc;
    const size_t i4 = (size_t)fi * 256 + tid;
    if (i4 < OH_NF4) {
      float4* base4 = (float4*)(out + OH_F4_BASE);
      base4[i4] = make_float4(0.f, 0.f, 0.f, 0.f);
    }
    if (fi == 0 && tid == 0) {   // stray head/tail of the 8-mod-16 region
      out[OH_OFF] = 0.f; out[OH_OFF + 1] = 0.f;
      out[OH_F4_BASE + 4 * (size_t)OH_NF4] = 0.f;
      out[OH_F4_BASE + 4 * (size_t)OH_NF4 + 1] = 0.f;
    }
    return;
  }

  // ---- COMPUTE (ci in [0,1024)) ----
  const int ci = q6;
  const int b = ci >> 5;
  const int hw0 = (ci & 31) << 7;
  const int w = tid >> 6, l = tid & 63, q = l & 15, g = l >> 4;

  // A fragments: 2 point-tiles x 2 ksteps, fp16 hi/lo.
  half8 ah[2][2], al[2][2];
  {
    const float* xb = in + ((size_t)b << 18);
#pragma unroll
    for (int a = 0; a < 2; ++a) {
      const int hw = hw0 + w * 32 + a * 16 + q;
#pragma unroll
      for (int ks = 0; ks < 2; ++ks) {
#pragma unroll
        for (int i = 0; i < 8; ++i) {
          float v = xb[((size_t)(ks * 32 + g * 8 + i) << 12) + hw];
          _Float16 h = (_Float16)v;
          ah[a][ks][i] = h;
          al[a][ks][i] = (_Float16)(v - (float)h);
        }
      }
    }
  }

  float bd0[4], bd1[4];
  int bk0[4], bk1[4];
#pragma unroll
  for (int j = 0; j < 4; ++j) { bd0[j] = bd1[j] = 3.4e38f; bk0[j] = bk1[j] = 0; }

  const int boff = q * 64 + g * 16;            // dense 1KB per wave-load

  for (int tb = 0; tb < 64; ++tb) {
    const char* tbase = cb2 + tb * 4096 + boff;
    half8 bh0 = *(const half8*)(tbase);
    half8 bh1 = *(const half8*)(tbase + 1024);
    half8 bl0 = *(const half8*)(tbase + 2048);
    half8 bl1 = *(const half8*)(tbase + 3072);
    const int code = tb * 16 + q;
    const float cn = cnorm[code];
    const f32x4 z = {0.f, 0.f, 0.f, 0.f};
    // a = 0: dot = xh.ch + xl.ch + xh.cl  (two 3-chains for ILP)
    f32x4 s = __builtin_amdgcn_mfma_f32_16x16x32_f16(ah[0][0], bh0, z, 0, 0, 0);
    s = __builtin_amdgcn_mfma_f32_16x16x32_f16(al[0][0], bh0, s, 0, 0, 0);
    s = __builtin_amdgcn_mfma_f32_16x16x32_f16(ah[0][0], bl0, s, 0, 0, 0);
    f32x4 t = __builtin_amdgcn_mfma_f32_16x16x32_f16(ah[0][1], bh1, z, 0, 0, 0);
    t = __builtin_amdgcn_mfma_f32_16x16x32_f16(al[0][1], bh1, t, 0, 0, 0);
    t = __builtin_amdgcn_mfma_f32_16x16x32_f16(ah[0][1], bl1, t, 0, 0, 0);
    s = s + t;
#pragma unroll
    for (int j = 0; j < 4; ++j) {
      float d = fmaf(-2.f, s[j], cn);
      if (d < bd0[j]) { bd0[j] = d; bk0[j] = code; }
    }
    // a = 1
    f32x4 u = __builtin_amdgcn_mfma_f32_16x16x32_f16(ah[1][0], bh0, z, 0, 0, 0);
    u = __builtin_amdgcn_mfma_f32_16x16x32_f16(al[1][0], bh0, u, 0, 0, 0);
    u = __builtin_amdgcn_mfma_f32_16x16x32_f16(ah[1][0], bl0, u, 0, 0, 0);
    f32x4 v = __builtin_amdgcn_mfma_f32_16x16x32_f16(ah[1][1], bh1, z, 0, 0, 0);
    v = __builtin_amdgcn_mfma_f32_16x16x32_f16(al[1][1], bh1, v, 0, 0, 0);
    v = __builtin_amdgcn_mfma_f32_16x16x32_f16(ah[1][1], bl1, v, 0, 0, 0);
    u = u + v;
#pragma unroll
    for (int j = 0; j < 4; ++j) {
      float d = fmaf(-2.f, u[j], cn);
      if (d < bd1[j]) { bd1[j] = d; bk1[j] = code; }
    }
  }

  // Butterfly argmin across the 16 code-residues (q = lane&15).
  // Equal distances -> lower code index (reference: first-index argmax).
#pragma unroll
  for (int m = 1; m < 16; m <<= 1) {
#pragma unroll
    for (int j = 0; j < 4; ++j) {
      float od = __shfl_xor(bd0[j], m, 64);
      int ok = __shfl_xor(bk0[j], m, 64);
      if (od < bd0[j] || (od == bd0[j] && ok < bk0[j])) { bd0[j] = od; bk0[j] = ok; }
      od = __shfl_xor(bd1[j], m, 64);
      ok = __shfl_xor(bk1[j], m, 64);
      if (od < bd1[j] || (od == bd1[j] && ok < bk1[j])) { bd1[j] = od; bk1[j] = ok; }
    }
  }
  if (q == 0) {
#pragma unroll
    for (int j = 0; j < 4; ++j) {
      bestk_s[w * 32 + g * 4 + j] = bk0[j];          // a=0 tile
      bestk_s[w * 32 + 16 + g * 4 + j] = bk1[j];     // a=1 tile
    }
  }
  __syncthreads();

  // ---- Epilogue: idx, hist, q_st, loss partial ----
  const int p = tid & 127, hf = tid >> 7;
  const int kq = bestk_s[p];
  if (hf == 0) {
    idx[ci * 128 + p] = kq;
    atomicAdd(&hist[kq], 1);   // integer: deterministic
  }
  float lsum = 0.f;
  {
    const float* xb = in + ((size_t)b << 18) + hw0 + p;
    float* yb = out + Q_OFF + ((size_t)b << 18) + hw0 + p;
    const float* qrow = cb + (size_t)kq * 64;
#pragma unroll
    for (int c = 0; c < 32; ++c) {
      const int cc = hf * 32 + c;
      float x = xb[(size_t)cc << 12];
      float f = qrow[cc] - x;
      lsum += f * f;
      yb[(size_t)cc << 12] = x + f;   // fl(x + fl(q-x)) as reference
    }
  }
  red[tid] = lsum;
  __syncthreads();
#pragma unroll
  for (int sft = 128; sft > 0; sft >>= 1) {
    if (tid < sft) red[tid] += red[tid + sft];
    __syncthreads();
  }
  if (tid == 0) partial[ci] = red[0];
}

// Merged ones-scatter + finalize: blocks 0..511 scatter the 131072 ones
// (zeros complete — kernel boundary orders us after k1_mega); block 512
// reduces loss partials and hist->perplexity (same trees as R14, absmax 0.0).
__global__ __launch_bounds__(256) void k_final(const int* __restrict__ idx,
                                               const int* __restrict__ hist,
                                               const float* __restrict__ partial,
                                               float* __restrict__ out) {
  const int tid = threadIdx.x;
  const int bid = blockIdx.x;
  if (bid < 512) {
    int n = bid * 256 + tid;
    int k = idx[n];
    int b = n >> 12;
    int pos = n & 4095;
    out[OH_OFF + ((((size_t)b << 10) + (size_t)k) << 12) + pos] = 1.0f;
    return;
  }

  __shared__ float red[256];
  // loss = 0.25 * mean((q-x)^2)
  float s = (partial[tid] + partial[tid + 512]) +
            (partial[tid + 256] + partial[tid + 768]);
  red[tid] = s;
  __syncthreads();
#pragma unroll
  for (int st = 128; st > 0; st >>= 1) {
    if (tid < st) red[tid] += red[tid + st];
    __syncthreads();
  }
  if (tid == 0) out[0] = 0.25f * (red[0] / LOSS_N);
  __syncthreads();

  // perplexity = exp(-sum p*log(p+1e-10)), p = count / 2^17 (exact)
  const float invn = 1.0f / 131072.0f;
  float p0 = (float)hist[tid] * invn;
  float p1 = (float)hist[tid + 256] * invn;
  float p2 = (float)hist[tid + 512] * invn;
  float p3 = (float)hist[tid + 768] * invn;
  float e = (p0 * logf(p0 + 1e-10f) + p2 * logf(p2 + 1e-10f)) +
            (p1 * logf(p1 + 1e-10f) + p3 * logf(p3 + 1e-10f));
  red[tid] = e;
  __syncthreads();
#pragma unroll
  for (int st = 128; st > 0; st >>= 1) {
    if (tid < st) red[tid] += red[tid + st];
    __syncthreads();
  }
  if (tid == 0) out[PERP_OFF] = expf(-red[0]);
}

extern "C" void kernel_launch(void* const* d_in, const int* in_sizes, int n_in,
                              void* d_out, int out_size, void* d_ws, size_t ws_size,
                              hipStream_t stream) {
  const float* in = (const float*)d_in[0];
  const float* cb = (const float*)d_in[1];
  float* out = (float*)d_out;

  float* cnorm   = (float*)d_ws;
  int*   hist    = (int*)d_ws + 1024;
  float* partial = (float*)d_ws + 2048;
  char*  cb2b    = (char*)d_ws + CB2_OFF_B;
  int*   idx     = (int*)d_ws + IDX_OFF_W;

  k0_prep<<<4, 256, 0, stream>>>(cb, cnorm, hist, cb2b);
  k1_mega<<<GRID_TOT, 256, 0, stream>>>(in, cb, cb2b, cnorm, hist, partial,
                                        idx, out);
  k_final<<<513, 256, 0, stream>>>(idx, hist, partial, out);
}